// Round 1
// 222.440 us; speedup vs baseline: 1.1263x; 1.1263x over previous
//
#include <hip/hip_runtime.h>

typedef unsigned short u16;
typedef __attribute__((ext_vector_type(8))) short bf16x8;
typedef __attribute__((ext_vector_type(4))) float f32x4;

__device__ __forceinline__ float bf2f(u16 u) {
  union { unsigned u; float f; } c; c.u = ((unsigned)u) << 16; return c.f;
}
__device__ __forceinline__ u16 f2bf(float f) {
  union { float f; unsigned u; } c; c.f = f;
  unsigned u = c.u;
  return (u16)((u + 0x7FFFu + ((u >> 16) & 1u)) >> 16);
}
// async global->LDS, 16B per lane; LDS dest = wave-uniform base + lane*16
__device__ __forceinline__ void gld16(const void* g, void* l) {
  __builtin_amdgcn_global_load_lds(
      (__attribute__((address_space(1))) void*)g,
      (__attribute__((address_space(3))) void*)l, 16, 0, 0);
}

#define BB 32      // batch
#define CC 256     // channels
#define NN 1024    // H*W

// ---------------- 0. convert weights/biases fp32 -> bf16 --------------------
__global__ __launch_bounds__(256) void convert_w_kernel(
    const float* __restrict__ Wk, const float* __restrict__ bk,
    const float* __restrict__ Wp, const float* __restrict__ bp,
    u16* __restrict__ Wkb, u16* __restrict__ bkb,
    u16* __restrict__ Wpb, u16* __restrict__ bpb)
{
  int b = blockIdx.x, t = threadIdx.x;
  const float* src; u16* dst; int idx, n;
  if (b < 768)       { src = Wk; dst = Wkb; idx = b * 256 + t;        n = 196608; }
  else if (b < 771)  { src = bk; dst = bkb; idx = (b - 768) * 256 + t; n = 768;   }
  else if (b < 1027) { src = Wp; dst = Wpb; idx = (b - 771) * 256 + t; n = 65536; }
  else               { src = bp; dst = bpb; idx = t;                  n = 256;    }
  if (idx < n) dst[idx] = f2bf(src[idx]);
}

// ---------------- 1. BatchNorm stats: per-channel mean/var -> scale/shift ----
__global__ __launch_bounds__(256) void bn_stats_kernel(
    const float* __restrict__ x, const float* __restrict__ gamma,
    const float* __restrict__ beta, float* __restrict__ scl, float* __restrict__ sft)
{
  int c = blockIdx.x;
  int tid = threadIdx.x;
  float s = 0.f, q = 0.f;
  for (int g = tid; g < 8192; g += 256) {
    int b = g >> 8;
    int n = (g & 255) * 4;
    float4 v = *reinterpret_cast<const float4*>(x + (((size_t)(b * CC + c)) << 10) + n);
    s += v.x + v.y + v.z + v.w;
    q += v.x * v.x + v.y * v.y + v.z * v.z + v.w * v.w;
  }
  __shared__ float rs[256], rq[256];
  rs[tid] = s; rq[tid] = q;
  __syncthreads();
  for (int off = 128; off > 0; off >>= 1) {
    if (tid < off) { rs[tid] += rs[tid + off]; rq[tid] += rq[tid + off]; }
    __syncthreads();
  }
  if (tid == 0) {
    float mean = rs[0] * (1.f / 32768.f);
    float var  = rq[0] * (1.f / 32768.f) - mean * mean;
    float rstd = rsqrtf(var + 1e-5f);
    float g = gamma[c] * rstd;
    scl[c] = g;
    sft[c] = beta[c] - mean * g;
  }
}

// ---------------- 2. normalize + transpose [B,C,N] -> t[B,N,C] (bf16) -------
__global__ __launch_bounds__(256) void norm_transpose_kernel(
    const float* __restrict__ x, const float* __restrict__ scl,
    const float* __restrict__ sft, u16* __restrict__ t)
{
  __shared__ float tile[64][65];
  int b = blockIdx.z, n0 = blockIdx.x * 64, c0 = blockIdx.y * 64;
  int tid = threadIdx.x;
  int hi = tid >> 4, lo4 = (tid & 15) * 4;
  #pragma unroll
  for (int r = 0; r < 4; ++r) {
    int cl = r * 16 + hi;
    int c = c0 + cl;
    float4 v = *reinterpret_cast<const float4*>(
        x + (((size_t)(b * CC + c)) << 10) + n0 + lo4);
    float sc = scl[c], sh = sft[c];
    tile[cl][lo4 + 0] = v.x * sc + sh;
    tile[cl][lo4 + 1] = v.y * sc + sh;
    tile[cl][lo4 + 2] = v.z * sc + sh;
    tile[cl][lo4 + 3] = v.w * sc + sh;
  }
  __syncthreads();
  #pragma unroll
  for (int r = 0; r < 4; ++r) {
    int nl = r * 16 + hi;
    ushort4 o;
    o.x = f2bf(tile[lo4 + 0][nl]);
    o.y = f2bf(tile[lo4 + 1][nl]);
    o.z = f2bf(tile[lo4 + 2][nl]);
    o.w = f2bf(tile[lo4 + 3][nl]);
    *reinterpret_cast<ushort4*>(t + ((size_t)(b * NN + n0 + nl)) * CC + c0 + lo4) = o;
  }
}

// ---------------- 3. NT bf16 GEMM, m97 structure (global_load_lds staging) ---
// C[m,n] = f(scale * sum_k A[m,k]*B[n,k] + bias[n])
// mode 0: plain bf16 store
// mode 1: transposed store vt[rr>>10][col][rr&1023] (bf16, ushort4)
// mode 2: proj + residual: outf[(b*256+col)<<10 | n] = v + xres[...] (fp32)
__global__ __launch_bounds__(256) void gemm_nt_kernel(
    const u16* __restrict__ A, int lda, size_t sA,
    const u16* __restrict__ B, int ldb, size_t sB,
    u16* __restrict__ C, int ldc, size_t sC,
    int K, const u16* __restrict__ bias, float scale, int mode,
    const float* __restrict__ xres, float* __restrict__ outf)
{
  __shared__ u16 As[128 * 32];   // unpadded: global_load_lds needs lane-contiguous
  __shared__ u16 Bs[128 * 32];
  int tid = threadIdx.x;
  int m0 = blockIdx.x * 128, n0 = blockIdx.y * 128;
  const u16* Ab = A + (size_t)blockIdx.z * sA;
  const u16* Bb = B + (size_t)blockIdx.z * sB;
  u16* Cb = C + (size_t)blockIdx.z * sC;

  int lane = tid & 63, w = tid >> 6;
  int lq = lane & 15, quad = lane >> 4;
  int wm = (w >> 1) * 64, wn = (w & 1) * 64;
  int ar = lane >> 2, ac = (lane & 3) * 8;   // staging: 4 lanes/row, 16B each
  int rb = w * 32;                            // wave's 32-row staging slice

  f32x4 zero = {0.f, 0.f, 0.f, 0.f};
  f32x4 acc[4][4];
  #pragma unroll
  for (int i = 0; i < 4; ++i)
    #pragma unroll
    for (int j = 0; j < 4; ++j) acc[i][j] = zero;

  for (int k0 = 0; k0 < K; k0 += 32) {
    __syncthreads();   // previous tile's ds_reads complete before overwrite
    gld16(Ab + (size_t)(m0 + rb +      ar) * lda + k0 + ac, &As[(rb     ) * 32]);
    gld16(Ab + (size_t)(m0 + rb + 16 + ar) * lda + k0 + ac, &As[(rb + 16) * 32]);
    gld16(Bb + (size_t)(n0 + rb +      ar) * ldb + k0 + ac, &Bs[(rb     ) * 32]);
    gld16(Bb + (size_t)(n0 + rb + 16 + ar) * ldb + k0 + ac, &Bs[(rb + 16) * 32]);
    __syncthreads();   // compiler drains vmcnt before barrier
    bf16x8 af[4], bfr[4];
    #pragma unroll
    for (int i = 0; i < 4; ++i) {
      af[i]  = *reinterpret_cast<const bf16x8*>(&As[(wm + i * 16 + lq) * 32 + quad * 8]);
      bfr[i] = *reinterpret_cast<const bf16x8*>(&Bs[(wn + i * 16 + lq) * 32 + quad * 8]);
    }
    #pragma unroll
    for (int i = 0; i < 4; ++i)
      #pragma unroll
      for (int j = 0; j < 4; ++j)
        acc[i][j] = __builtin_amdgcn_mfma_f32_16x16x32_bf16(af[i], bfr[j], acc[i][j], 0, 0, 0);
  }

  #pragma unroll
  for (int j = 0; j < 4; ++j) {
    int col = n0 + wn + j * 16 + lq;
    float bv = bias ? bf2f(bias[col]) : 0.f;
    #pragma unroll
    for (int i = 0; i < 4; ++i) {
      int rbase = m0 + wm + i * 16 + quad * 4;
      if (mode == 2) {
        int b = rbase >> 10, n = rbase & 1023;
        size_t idx = (((size_t)(b * CC + col)) << 10) + n;
        float4 xv = *reinterpret_cast<const float4*>(xres + idx);
        float4 o;
        o.x = acc[i][j][0] * scale + bv + xv.x;
        o.y = acc[i][j][1] * scale + bv + xv.y;
        o.z = acc[i][j][2] * scale + bv + xv.z;
        o.w = acc[i][j][3] * scale + bv + xv.w;
        *reinterpret_cast<float4*>(outf + idx) = o;
      } else if (mode == 1) {
        int b = rbase >> 10, n = rbase & 1023;
        ushort4 o;
        o.x = f2bf(acc[i][j][0] * scale + bv);
        o.y = f2bf(acc[i][j][1] * scale + bv);
        o.z = f2bf(acc[i][j][2] * scale + bv);
        o.w = f2bf(acc[i][j][3] * scale + bv);
        *reinterpret_cast<ushort4*>(&Cb[(size_t)b * 262144 + (size_t)col * 1024 + n]) = o;
      } else {
        #pragma unroll
        for (int r = 0; r < 4; ++r)
          Cb[(size_t)(rbase + r) * ldc + col] = f2bf(acc[i][j][r] * scale + bv);
      }
    }
  }
}

// ---------------- 4. fused attention: O = softmax(Q K^T / 16) V -------------
// One block = 128 Q-rows of one batch; 4 waves x 32 rows. K/V tiles of 64
// staged in LDS via global_load_lds (pre-swizzled source, XOR-swizzled reads).
// Each wave owns full rows -> exact row sums, no atomics, no S in HBM.
__global__ __launch_bounds__(256, 1) void attn_kernel(
    const u16* __restrict__ qk,   // [B*1024, 512]: Q = cols 0:256, K = 256:512
    const u16* __restrict__ vt,   // [B, 256, 1024]: V^T per batch
    u16* __restrict__ o)          // [B*1024, 256]
{
  __shared__ __align__(16) u16 Ks[64 * 256];      // 32 KB  [kr][c], chunk^=(kr&7)
  __shared__ __align__(16) u16 Vs[256 * 64];      // 32 KB  [n][k],  chunk^=(n&7)
  __shared__ __align__(16) u16 Ps[4][32 * 64];    // 16 KB/4w  [q][kcol], chunk^=(q&7)

  int bid = blockIdx.x;
  // XCD swizzle: all 8 q-tiles of one batch land on one XCD (K/V L2-resident)
  int b  = (bid & 7) + 8 * ((bid >> 3) & 3);
  int qt = bid >> 5;
  int tid = threadIdx.x, lane = tid & 63, w = tid >> 6;
  int lq = lane & 15, hh = lane >> 4;

  const u16* qb = qk + ((size_t)b << 10) * 512;
  const u16* kb = qb + 256;
  const u16* vb = vt + ((size_t)b << 18);
  int q0 = qt * 128 + w * 32;

  // Q fragments in registers: A-frag row = lq, k = kk*32 + hh*8
  bf16x8 qf[2][8];
  #pragma unroll
  for (int qi = 0; qi < 2; ++qi)
    #pragma unroll
    for (int kk = 0; kk < 8; ++kk)
      qf[qi][kk] = *reinterpret_cast<const bf16x8*>(
          qb + (size_t)(q0 + qi * 16 + lq) * 512 + kk * 32 + hh * 8);

  f32x4 zero = {0.f, 0.f, 0.f, 0.f};
  f32x4 oacc[2][16];
  #pragma unroll
  for (int qi = 0; qi < 2; ++qi)
    #pragma unroll
    for (int nj = 0; nj < 16; ++nj) oacc[qi][nj] = zero;
  float runsum[2][4] = {{0.f, 0.f, 0.f, 0.f}, {0.f, 0.f, 0.f, 0.f}};

  u16* Pw = Ps[w];
  int wslot = tid & 192;   // wave-uniform slot base (w*64)

  #pragma unroll 1
  for (int kt = 0; kt < 16; ++kt) {
    __syncthreads();   // all waves done reading previous K/V tile
    // stage K tile: rows kt*64..+64, 256 cols; 32 chunks(16B)/row
    #pragma unroll
    for (int i = 0; i < 8; ++i) {
      int slot = i * 256 + tid;
      int r = slot >> 5, c = slot & 31;
      gld16(kb + (size_t)((kt * 64 + r)) * 512 + ((c ^ (r & 7)) << 3),
            &Ks[(i * 256 + wslot) * 8]);
    }
    // stage V tile: Vs[n][k] = vt[n][kt*64+k]; 8 chunks/row
    #pragma unroll
    for (int i = 0; i < 8; ++i) {
      int slot = i * 256 + tid;
      int n = slot >> 3, c = slot & 7;
      gld16(vb + (size_t)(n << 10) + kt * 64 + ((c ^ (n & 7)) << 3),
            &Vs[(i * 256 + wslot) * 8]);
    }
    __syncthreads();   // vmcnt drained by compiler before barrier

    // ---- S = Q K^T for wave's 32 rows x 64 kcols ----
    f32x4 sacc[2][4];
    #pragma unroll
    for (int qi = 0; qi < 2; ++qi)
      #pragma unroll
      for (int ni = 0; ni < 4; ++ni) sacc[qi][ni] = zero;
    #pragma unroll
    for (int kk = 0; kk < 8; ++kk) {
      bf16x8 kf[4];
      #pragma unroll
      for (int ni = 0; ni < 4; ++ni) {
        int r = ni * 16 + lq;
        kf[ni] = *reinterpret_cast<const bf16x8*>(
            &Ks[r * 256 + (((kk * 4 + hh) ^ (r & 7)) << 3)]);
      }
      #pragma unroll
      for (int qi = 0; qi < 2; ++qi)
        #pragma unroll
        for (int ni = 0; ni < 4; ++ni)
          sacc[qi][ni] = __builtin_amdgcn_mfma_f32_16x16x32_bf16(
              qf[qi][kk], kf[ni], sacc[qi][ni], 0, 0, 0);
    }

    // ---- P = exp(S/16), accumulate row sums, pack bf16 into wave-private LDS
    #pragma unroll
    for (int qi = 0; qi < 2; ++qi)
      #pragma unroll
      for (int ni = 0; ni < 4; ++ni)
        #pragma unroll
        for (int rr = 0; rr < 4; ++rr) {
          float p = __expf(sacc[qi][ni][rr] * 0.0625f);
          u16 pb = f2bf(p);
          runsum[qi][rr] += bf2f(pb);    // sum rounded values (matches PV input)
          int q = qi * 16 + hh * 4 + rr;
          int kcol = ni * 16 + lq;
          Pw[q * 64 + ((((kcol >> 3) ^ (q & 7)) << 3) | (kcol & 7))] = pb;
        }

    // ---- O += P V ----
    #pragma unroll
    for (int kk2 = 0; kk2 < 2; ++kk2) {
      bf16x8 pa[2];
      #pragma unroll
      for (int qi = 0; qi < 2; ++qi) {
        int q = qi * 16 + lq;
        pa[qi] = *reinterpret_cast<const bf16x8*>(
            &Pw[q * 64 + (((kk2 * 4 + hh) ^ (q & 7)) << 3)]);
      }
      #pragma unroll
      for (int nj = 0; nj < 16; ++nj) {
        int n = nj * 16 + lq;
        bf16x8 vf = *reinterpret_cast<const bf16x8*>(
            &Vs[n * 64 + (((kk2 * 4 + hh) ^ (n & 7)) << 3)]);
        #pragma unroll
        for (int qi = 0; qi < 2; ++qi)
          oacc[qi][nj] = __builtin_amdgcn_mfma_f32_16x16x32_bf16(
              pa[qi], vf, oacc[qi][nj], 0, 0, 0);
      }
    }
  }

  // ---- finalize: reduce row sums across the 16 kcol-lanes, scale, store ----
  #pragma unroll
  for (int qi = 0; qi < 2; ++qi)
    #pragma unroll
    for (int rr = 0; rr < 4; ++rr) {
      float s = runsum[qi][rr];
      s += __shfl_xor(s, 1, 64);
      s += __shfl_xor(s, 2, 64);
      s += __shfl_xor(s, 4, 64);
      s += __shfl_xor(s, 8, 64);
      runsum[qi][rr] = 1.f / s;
    }
  u16* ob = o + (size_t)((b << 10) + q0) * 256;
  #pragma unroll
  for (int qi = 0; qi < 2; ++qi)
    #pragma unroll
    for (int nj = 0; nj < 16; ++nj)
      #pragma unroll
      for (int rr = 0; rr < 4; ++rr)
        ob[(size_t)(qi * 16 + hh * 4 + rr) * 256 + nj * 16 + lq] =
            f2bf(oacc[qi][nj][rr] * runsum[qi][rr]);
}

extern "C" void kernel_launch(void* const* d_in, const int* in_sizes, int n_in,
                              void* d_out, int out_size, void* d_ws, size_t ws_size,
                              hipStream_t stream) {
  const float* x     = (const float*)d_in[0];
  const float* gamma = (const float*)d_in[1];
  const float* beta  = (const float*)d_in[2];
  const float* Wkqv  = (const float*)d_in[3];
  const float* bkqv  = (const float*)d_in[4];
  const float* Wproj = (const float*)d_in[5];
  const float* bproj = (const float*)d_in[6];
  float* out = (float*)d_out;          // fp32 [32,256,32,32]

  // ---- workspace layout ----
  char* ws = (char*)d_ws;
  float* scl    = (float*)ws;                   // 256 f32
  float* sft    = (float*)(ws + 1024);          // 256 f32
  u16* Wkb = (u16*)(ws + 4096);                 // 196608 bf16
  u16* bkb = Wkb + 196608;
  u16* Wpb = bkb + 768;
  u16* bpb = Wpb + 65536;
  u16* qk   = (u16*)(ws + 1048576);             // [32768,512] bf16 = 32 MB
  u16* vt   = qk + (size_t)32768 * 512;         // [32,256,1024] bf16 = 16 MB
  u16* o_pv = vt + (size_t)32 * 256 * 1024;     // [32768,256] bf16 = 16 MB
  u16* t = (u16*)d_out;   // bf16 scratch in d_out, dead before mode-2 writes

  // 0. weight conversion
  convert_w_kernel<<<dim3(1028), dim3(256), 0, stream>>>(
      Wkqv, bkqv, Wproj, bproj, Wkb, bkb, Wpb, bpb);
  // 1. BN stats
  bn_stats_kernel<<<dim3(256), dim3(256), 0, stream>>>(x, gamma, beta, scl, sft);
  // 2. normalize + transpose -> t [B,N,C]
  norm_transpose_kernel<<<dim3(16, 4, 32), dim3(256), 0, stream>>>(x, scl, sft, t);
  // 3a. qk = t @ Wkqv[0:512]^T + b[0:512]
  gemm_nt_kernel<<<dim3(256, 4, 1), dim3(256), 0, stream>>>(
      t, 256, 0, Wkb, 256, 0, qk, 512, 0, 256, bkb, 1.0f, 0, nullptr, nullptr);
  // 3b. vt[b,c,n] = (t @ Wkqv[512:768]^T + b[512:768])^T
  gemm_nt_kernel<<<dim3(256, 2, 1), dim3(256), 0, stream>>>(
      t, 256, 0, Wkb + 512 * 256, 256, 0, vt, 0, 0, 256, bkb + 512, 1.0f, 1,
      nullptr, nullptr);
  // 4. fused attention: o_pv = softmax(Q K^T / 16) V   (bf16)
  attn_kernel<<<dim3(256), dim3(256), 0, stream>>>(qk, vt, o_pv);
  // 5. fused proj + residual: out[b,c,n] = (o_pv @ Wproj^T + bproj)[n,c] + x[b,c,n]
  gemm_nt_kernel<<<dim3(256, 2, 1), dim3(256), 0, stream>>>(
      o_pv, 256, 0, Wpb, 256, 0, nullptr, 0, 0, 256, bpb, 1.0f, 2, x, out);
}